// Round 2
// baseline (310.987 us; speedup 1.0000x reference)
//
#include <hip/hip_runtime.h>

#define IMG_W 512
#define IMG_H 512
#define TILE 88      // output tile per block
#define HALO 20      // >= 19 dilation steps of halo
#define NSTEP 19     // dilations accumulated (k=1..19; k=0 term is x itself)
#define RH 8
#define RW 8
#define REG 128      // region = 128x128, threads 16x16, 8x8 px/thread in regs

typedef float f2 __attribute__((ext_vector_type(2)));

__device__ __forceinline__ float max3f(float a, float b, float c) {
    return fmaxf(fmaxf(a, b), c);   // -> v_max3_f32
}

// DPP lane shifts within 16-lane rows (tx = lane%16). bound_ctrl=1: lanes with
// no source get 0.0f — lands only in region cols 0/127 (halo, garbage-tolerant)
// and avoids the old-dest tie-copy the bound_ctrl=0 form forces.
__device__ __forceinline__ float dpp_shr1(float v) { // receive from lane-1 (left nbr)
    int i = __builtin_bit_cast(int, v);
    i = __builtin_amdgcn_update_dpp(0, i, 0x111, 0xf, 0xf, true); // row_shr:1
    return __builtin_bit_cast(float, i);
}
__device__ __forceinline__ float dpp_shl1(float v) { // receive from lane+1 (right nbr)
    int i = __builtin_bit_cast(int, v);
    i = __builtin_amdgcn_update_dpp(0, i, 0x101, 0xf, 0xf, true); // row_shl:1
    return __builtin_bit_cast(float, i);
}

// Horizontal 3-max. NO masking: only A needs to stay zeroed outside the image;
// h at in-image columns only ever reads A values that are already correct.
__device__ __forceinline__ void hrow(const float (&Ar)[RW], float (&h)[RW]) {
    float hl = dpp_shr1(Ar[RW - 1]);
    float hr = dpp_shl1(Ar[0]);
    h[0] = max3f(hl, Ar[0], Ar[1]);
    #pragma unroll
    for (int c = 1; c < RW - 1; ++c) h[c] = max3f(Ar[c - 1], Ar[c], Ar[c + 1]);
    h[RW - 1] = max3f(Ar[RW - 2], Ar[RW - 1], hr);
}

// One output row: D[r] = max3(h[r-1], h[r], h[r+1]), re-mask A, accumulate.
// Masks applied ONCE here (not in hrow): XM -> column mask (packed pk_mul),
// YM -> row mask, only for threads whose rows straddle the image boundary
// (whole waves with needR==false skip via execz).
template<bool XM, bool YM>
__device__ __forceinline__ void rowop(const float (&ha)[RW], const float (&hb)[RW],
                                      const float (&hcn)[RW], float (&Ar)[RW],
                                      f2 (&accr)[RW / 2], const f2 (&cm2)[RW / 2],
                                      float rm, bool needR) {
    f2 v[RW / 2];
    #pragma unroll
    for (int c2 = 0; c2 < RW / 2; ++c2) {
        float v0 = max3f(ha[2 * c2],     hb[2 * c2],     hcn[2 * c2]);
        float v1 = max3f(ha[2 * c2 + 1], hb[2 * c2 + 1], hcn[2 * c2 + 1]);
        v[c2].x = v0; v[c2].y = v1;
    }
    if (XM) {
        #pragma unroll
        for (int c2 = 0; c2 < RW / 2; ++c2) v[c2] *= cm2[c2];   // v_pk_mul_f32
    }
    if (YM) {
        if (needR) {
            f2 rb; rb.x = rm; rb.y = rm;
            #pragma unroll
            for (int c2 = 0; c2 < RW / 2; ++c2) v[c2] *= rb;
        }
    }
    #pragma unroll
    for (int c2 = 0; c2 < RW / 2; ++c2) {
        accr[c2] += v[c2];                                      // v_pk_add_f32
        Ar[2 * c2] = v[c2].x; Ar[2 * c2 + 1] = v[c2].y;
    }
}

template<bool XM, bool YM>
__device__ __forceinline__ void body(const float* __restrict__ xc, float* __restrict__ oc,
                                     int gx0, int gy0, int tx, int ty,
                                     float4 (*topH4)[2][16][16], float4 (*botH4)[2][16][16]) {
    const int rx = tx * RW;      // chunk origin in region coords
    const int ry = ty * RH;
    const int gx = gx0 + rx;     // chunk origin in global coords
    const int gy = gy0 + ry;

    float A[RH][RW];     // current image
    f2 acc[RH][RW / 2];  // sum of D_k (packed pairs)
    float colm[RW], rowm[RH];
    f2 cm2[RW / 2];
    bool needR = false;

    if (XM) {
        #pragma unroll
        for (int c = 0; c < RW; ++c) {
            int xx = gx + c;
            colm[c] = (xx >= 0 && xx < IMG_W) ? 1.f : 0.f;
        }
        #pragma unroll
        for (int c2 = 0; c2 < RW / 2; ++c2) { cm2[c2].x = colm[2 * c2]; cm2[c2].y = colm[2 * c2 + 1]; }
    }
    if (YM) {
        #pragma unroll
        for (int r = 0; r < RH; ++r) {
            int yy = gy + r;
            rowm[r] = (yy >= 0 && yy < IMG_H) ? 1.f : 0.f;
        }
        needR = (gy < 0) || (gy + RH > IMG_H);
    }

    if (XM || YM) {
        const bool fullin = (gx >= 0) && (gx + RW <= IMG_W) && (gy >= 0) && (gy + RH <= IMG_H);
        if (fullin) {
            #pragma unroll
            for (int r = 0; r < RH; ++r) {
                const float4* rp = (const float4*)(xc + (size_t)(gy + r) * IMG_W + gx);
                float4 v0 = rp[0], v1 = rp[1];
                A[r][0] = v0.x; A[r][1] = v0.y; A[r][2] = v0.z; A[r][3] = v0.w;
                A[r][4] = v1.x; A[r][5] = v1.y; A[r][6] = v1.z; A[r][7] = v1.w;
            }
        } else {
            #pragma unroll
            for (int r = 0; r < RH; ++r) {
                const int yr = gy + r;
                const int yy = min(max(yr, 0), IMG_H - 1);
                float rmv = 1.f;
                if (YM) rmv = (yr >= 0 && yr < IMG_H) ? 1.f : 0.f;
                const float* rp = xc + (size_t)yy * IMG_W;
                #pragma unroll
                for (int c = 0; c < RW; ++c) {
                    const int xr = gx + c;
                    const int xx = min(max(xr, 0), IMG_W - 1);
                    float m = rmv;
                    if (XM) m *= colm[c];
                    A[r][c] = rp[xx] * m;
                }
            }
        }
    } else {
        #pragma unroll
        for (int r = 0; r < RH; ++r) {
            const float4* rp = (const float4*)(xc + (size_t)(gy + r) * IMG_W + gx);
            float4 v0 = rp[0], v1 = rp[1];
            A[r][0] = v0.x; A[r][1] = v0.y; A[r][2] = v0.z; A[r][3] = v0.w;
            A[r][4] = v1.x; A[r][5] = v1.y; A[r][6] = v1.z; A[r][7] = v1.w;
        }
    }
    #pragma unroll
    for (int r = 0; r < RH; ++r) {
        #pragma unroll
        for (int c2 = 0; c2 < RW / 2; ++c2) { acc[r][c2].x = A[r][2 * c2]; acc[r][c2].y = A[r][2 * c2 + 1]; }
    }

    #pragma unroll 1
    for (int s = 0; s < NSTEP; ++s) {
        const int buf = s & 1;
        float hc[RW], h7[RW];
        hrow(A[0], hc);
        hrow(A[RH - 1], h7);
        topH4[buf][0][ty][tx] = make_float4(hc[0], hc[1], hc[2], hc[3]);
        topH4[buf][1][ty][tx] = make_float4(hc[4], hc[5], hc[6], hc[7]);
        botH4[buf][0][ty][tx] = make_float4(h7[0], h7[1], h7[2], h7[3]);
        botH4[buf][1][ty][tx] = make_float4(h7[4], h7[5], h7[6], h7[7]);
        __syncthreads();
        // Issue the neighbor reads NOW; they are consumed only at rows 7 and 0,
        // ~6 rows of independent VALU work later (lgkmcnt latency hidden).
        const int tyu = ty > 0  ? ty - 1 : 0;    // clamped: region-edge garbage OK
        const int tyd = ty < 15 ? ty + 1 : 15;
        float4 u0 = botH4[buf][0][tyu][tx], u1 = botH4[buf][1][tyu][tx];
        float4 d0 = topH4[buf][0][tyd][tx], d1 = topH4[buf][1][tyd][tx];

        float hup[RW], hcur[RW], h6s[RW];
        hrow(A[RH - 2], hcur);               // h6
        #pragma unroll
        for (int c = 0; c < RW; ++c) { hup[c] = h7[c]; h6s[c] = hcur[c]; }

        // rows 6..1 downward; rolling window (hup=h[r+1], hcur=h[r], hn=h[r-1])
        #pragma unroll
        for (int r = RH - 2; r >= 1; --r) {
            float hn[RW];
            if (r > 1) {
                hrow(A[r - 1], hn);
            } else {
                #pragma unroll
                for (int c = 0; c < RW; ++c) hn[c] = hc[c];   // h0 already computed
            }
            rowop<XM, YM>(hn, hcur, hup, A[r], acc[r], cm2, YM ? rowm[r] : 1.f, needR);
            #pragma unroll
            for (int c = 0; c < RW; ++c) { hup[c] = hcur[c]; hcur[c] = hn[c]; }
        }
        // row 7 (needs LDS hbot) then row 0 (needs LDS hm1)
        {
            float hb[RW] = {d0.x, d0.y, d0.z, d0.w, d1.x, d1.y, d1.z, d1.w};
            rowop<XM, YM>(h6s, h7, hb, A[RH - 1], acc[RH - 1], cm2, YM ? rowm[RH - 1] : 1.f, needR);
        }
        {
            float hm[RW] = {u0.x, u0.y, u0.z, u0.w, u1.x, u1.y, u1.z, u1.w};
            // post-loop: hup == h1
            rowop<XM, YM>(hm, hc, hup, A[0], acc[0], cm2, YM ? rowm[0] : 1.f, needR);
        }
        // no second barrier: next step uses the other LDS buffer; re-writes of
        // THIS buffer happen after the next step's barrier.
    }

    // Epilogue: store central TILE x TILE (region coords [HALO, HALO+TILE))
    if (XM || YM) {
        #pragma unroll
        for (int r = 0; r < RH; ++r) {
            const int rr = ry + r;
            const int yy = gy0 + rr;
            if (rr >= HALO && rr < HALO + TILE && yy < IMG_H) {
                #pragma unroll
                for (int c = 0; c < RW; ++c) {
                    const int cc = rx + c;
                    const int xx = gx0 + cc;
                    if (cc >= HALO && cc < HALO + TILE && xx < IMG_W) {
                        float av = (c & 1) ? acc[r][c >> 1].y : acc[r][c >> 1].x;
                        oc[(size_t)yy * IMG_W + xx] = 0.05f * av;
                    }
                }
            }
        }
    } else {
        const f2 sc = {0.05f, 0.05f};
        #pragma unroll
        for (int r = 0; r < RH; ++r) {
            const int rr = ry + r;
            if (rr < HALO || rr >= HALO + TILE) continue;
            const int yy = gy0 + rr;
            float* rowp = oc + (size_t)yy * IMG_W + gx;
            f2 a0 = acc[r][0] * sc, a1 = acc[r][1] * sc;
            f2 a2 = acc[r][2] * sc, a3 = acc[r][3] * sc;
            if (tx >= 3 && tx <= 12) {
                ((float4*)rowp)[0] = make_float4(a0.x, a0.y, a1.x, a1.y);
                ((float4*)rowp)[1] = make_float4(a2.x, a2.y, a3.x, a3.y);
            } else if (tx == 2) {        // cols 16..23, valid 20..23 -> c=4..7
                ((float4*)rowp)[1] = make_float4(a2.x, a2.y, a3.x, a3.y);
            } else if (tx == 13) {       // cols 104..111, valid 104..107 -> c=0..3
                ((float4*)rowp)[0] = make_float4(a0.x, a0.y, a1.x, a1.y);
            }
        }
    }
}

__global__ __launch_bounds__(256, 2)
void blur_outwards_kernel(const float* __restrict__ x, float* __restrict__ out) {
    __shared__ float4 topH4[2][2][16][16];   // 16 KB
    __shared__ float4 botH4[2][2][16][16];   // 16 KB

    const int tid = threadIdx.x;
    const int tx = tid & 15;
    const int ty = tid >> 4;

    const int ch  = blockIdx.z;                       // 0..95
    const int gx0 = (int)blockIdx.x * TILE - HALO;
    const int gy0 = (int)blockIdx.y * TILE - HALO;

    const float* __restrict__ xc = x + (size_t)ch * (IMG_W * IMG_H);
    float* __restrict__ oc = out + (size_t)ch * (IMG_W * IMG_H);

    const bool xe = (gx0 < 0) || (gx0 + REG > IMG_W);
    const bool ye = (gy0 < 0) || (gy0 + REG > IMG_H);
    if (!xe && !ye)      body<false, false>(xc, oc, gx0, gy0, tx, ty, topH4, botH4);
    else if (xe && !ye)  body<true,  false>(xc, oc, gx0, gy0, tx, ty, topH4, botH4);
    else if (!xe && ye)  body<false, true >(xc, oc, gx0, gy0, tx, ty, topH4, botH4);
    else                 body<true,  true >(xc, oc, gx0, gy0, tx, ty, topH4, botH4);
}

extern "C" void kernel_launch(void* const* d_in, const int* in_sizes, int n_in,
                              void* d_out, int out_size, void* d_ws, size_t ws_size,
                              hipStream_t stream) {
    const float* x = (const float*)d_in[0];
    float* out = (float*)d_out;
    dim3 grid((IMG_W + TILE - 1) / TILE,   // 6
              (IMG_H + TILE - 1) / TILE,   // 6
              96);                          // 32 batch * 3 channels
    blur_outwards_kernel<<<grid, 256, 0, stream>>>(x, out);
}